// Round 1
// baseline (3089.750 us; speedup 1.0000x reference)
//
#include <hip/hip_runtime.h>

#define EPS_BN 1e-5f

// ---------------------------------------------------------------------------
// Kernel 1: fused gather-matvec-scatter.
// One thread per input voxel. W (8x32x64 fp32 = 64KB) staged in LDS.
// Swizzle: channel-group slot = (g + j) & 15 so that lanes with different j
// (random per lane) read disjoint banks: bank(float4 start) = 4*((g+j)&15)%32,
// j spans 0..7 -> 8 consecutive slots mod 16 -> exactly covers all 32 banks.
// ---------------------------------------------------------------------------
__global__ __launch_bounds__(256) void conv_scatter(
    const float* __restrict__ x, const float* __restrict__ W,
    const int* __restrict__ k_idx, const int* __restrict__ out_idx,
    float* __restrict__ out, int n_vox)
{
    __shared__ float4 sW[4096];               // 8 * 32 * 16 float4 = 64 KB
    const float4* Wv = (const float4*)W;      // Wv[j*512 + k*16 + g]
    for (int i = threadIdx.x; i < 4096; i += 256) {
        int j = i >> 9;                       // kernel offset 0..7
        int g = i & 15;                       // channel group 0..15
        sW[(i & ~15) | ((g + j) & 15)] = Wv[i];
    }
    __syncthreads();

    const int stride = gridDim.x * 256;
    for (int v = blockIdx.x * 256 + threadIdx.x; v < n_vox; v += stride) {
        const int j = k_idx[v];
        const int o = out_idx[v];
        const float4* xp = (const float4*)(x + (size_t)v * 32);

        float4 acc[16];
#pragma unroll
        for (int g = 0; g < 16; ++g) acc[g] = make_float4(0.f, 0.f, 0.f, 0.f);

        const int base = j << 9;
#pragma unroll
        for (int ko = 0; ko < 8; ++ko) {
            const float4 xk4 = xp[ko];
#pragma unroll
            for (int ki = 0; ki < 4; ++ki) {
                const float xk = (ki == 0) ? xk4.x : (ki == 1) ? xk4.y
                               : (ki == 2) ? xk4.z : xk4.w;
                const int rowbase = base + ((ko * 4 + ki) << 4);
#pragma unroll
                for (int g = 0; g < 16; ++g) {
                    const float4 w = sW[rowbase + ((g + j) & 15)];
                    acc[g].x = fmaf(xk, w.x, acc[g].x);
                    acc[g].y = fmaf(xk, w.y, acc[g].y);
                    acc[g].z = fmaf(xk, w.z, acc[g].z);
                    acc[g].w = fmaf(xk, w.w, acc[g].w);
                }
            }
        }

        float* ob = out + (size_t)o * 64;
#pragma unroll
        for (int g = 0; g < 16; ++g) {
            atomicAdd(ob + 4 * g + 0, acc[g].x);
            atomicAdd(ob + 4 * g + 1, acc[g].y);
            atomicAdd(ob + 4 * g + 2, acc[g].z);
            atomicAdd(ob + 4 * g + 3, acc[g].w);
        }
    }
}

// ---------------------------------------------------------------------------
// Kernel 2: per-channel sum and sum-of-squares over the accumulator.
// ws[0..63] = sum, ws[64..127] = sumsq (pre-zeroed by memset).
// ---------------------------------------------------------------------------
__global__ __launch_bounds__(256) void stats_kernel(
    const float* __restrict__ out, float* __restrict__ ws, int num_out)
{
    __shared__ float s_red[128];
    if (threadIdx.x < 128) s_red[threadIdx.x] = 0.f;
    __syncthreads();

    const int cg   = threadIdx.x & 15;   // channel group: channels 4cg..4cg+3
    const int rowt = threadIdx.x >> 4;   // 0..15 rows handled per block slice

    float4 sum = make_float4(0.f, 0.f, 0.f, 0.f);
    float4 sq  = make_float4(0.f, 0.f, 0.f, 0.f);
    const float4* o4 = (const float4*)out;
    for (int r = blockIdx.x * 16 + rowt; r < num_out; r += gridDim.x * 16) {
        const float4 v = o4[(size_t)r * 16 + cg];
        sum.x += v.x; sum.y += v.y; sum.z += v.z; sum.w += v.w;
        sq.x  += v.x * v.x; sq.y += v.y * v.y;
        sq.z  += v.z * v.z; sq.w += v.w * v.w;
    }

    atomicAdd(&s_red[4 * cg + 0], sum.x);
    atomicAdd(&s_red[4 * cg + 1], sum.y);
    atomicAdd(&s_red[4 * cg + 2], sum.z);
    atomicAdd(&s_red[4 * cg + 3], sum.w);
    atomicAdd(&s_red[64 + 4 * cg + 0], sq.x);
    atomicAdd(&s_red[64 + 4 * cg + 1], sq.y);
    atomicAdd(&s_red[64 + 4 * cg + 2], sq.z);
    atomicAdd(&s_red[64 + 4 * cg + 3], sq.w);
    __syncthreads();

    if (threadIdx.x < 128) atomicAdd(&ws[threadIdx.x], s_red[threadIdx.x]);
}

// ---------------------------------------------------------------------------
// Kernel 3: fold stats into per-channel scale/shift.
// result = (acc + bias - mean_out) * rsqrt(var) * gamma + beta
//        = acc * a + b   with  a = gamma*rsqrt(var+eps), b = beta - mean_acc*a
// (bias cancels: mean_out = mean_acc + bias; var unaffected by bias)
// ws[128..191] = a, ws[192..255] = b.
// ---------------------------------------------------------------------------
__global__ void finalize_kernel(const float* __restrict__ gamma,
                                const float* __restrict__ beta,
                                float* __restrict__ ws, float inv_n)
{
    const int c = threadIdx.x;   // 64 threads
    const float mean_acc = ws[c] * inv_n;
    const float var = ws[64 + c] * inv_n - mean_acc * mean_acc;
    const float a = gamma[c] * rsqrtf(var + EPS_BN);
    ws[128 + c] = a;
    ws[192 + c] = beta[c] - mean_acc * a;
}

// ---------------------------------------------------------------------------
// Kernel 4: in-place affine + ReLU.
// ---------------------------------------------------------------------------
__global__ __launch_bounds__(256) void apply_kernel(
    float* __restrict__ out, const float* __restrict__ ws, int n4)
{
    const int tid = blockIdx.x * 256 + threadIdx.x;
    const int stride = gridDim.x * 256;          // multiple of 16 -> cg fixed
    const int cg = tid & 15;
    const float4 a = ((const float4*)(ws + 128))[cg];
    const float4 b = ((const float4*)(ws + 192))[cg];
    float4* o4 = (float4*)out;
    for (int i = tid; i < n4; i += stride) {
        float4 v = o4[i];
        v.x = fmaxf(fmaf(v.x, a.x, b.x), 0.f);
        v.y = fmaxf(fmaf(v.y, a.y, b.y), 0.f);
        v.z = fmaxf(fmaf(v.z, a.z, b.z), 0.f);
        v.w = fmaxf(fmaf(v.w, a.w, b.w), 0.f);
        o4[i] = v;
    }
}

extern "C" void kernel_launch(void* const* d_in, const int* in_sizes, int n_in,
                              void* d_out, int out_size, void* d_ws, size_t ws_size,
                              hipStream_t stream)
{
    const float* x     = (const float*)d_in[0];
    const float* W     = (const float*)d_in[1];
    // d_in[2] = bias: cancels under BN, unused.
    const float* gamma = (const float*)d_in[3];
    const float* beta  = (const float*)d_in[4];
    const int* k_idx   = (const int*)d_in[5];
    const int* out_idx = (const int*)d_in[6];

    const int n_vox   = in_sizes[5];
    const int num_out = out_size / 64;
    float* out = (float*)d_out;
    float* ws  = (float*)d_ws;

    // Accumulator is d_out itself (harness poisons it; we zero it).
    hipMemsetAsync(d_out, 0, (size_t)out_size * sizeof(float), stream);
    hipMemsetAsync(d_ws, 0, 128 * sizeof(float), stream);

    conv_scatter<<<512, 256, 0, stream>>>(x, W, k_idx, out_idx, out, n_vox);
    stats_kernel<<<256, 256, 0, stream>>>(out, ws, num_out);
    finalize_kernel<<<1, 64, 0, stream>>>(gamma, beta, ws, 1.0f / (float)num_out);
    apply_kernel<<<1024, 256, 0, stream>>>(out, ws, out_size / 4);
}

// Round 2
// 674.102 us; speedup vs baseline: 4.5835x; 4.5835x over previous
//
#include <hip/hip_runtime.h>

#define EPS_BN 1e-5f

// ===========================================================================
// Pipeline: CSR-invert the out_idx map (hist -> scan -> scatter-perm), then a
// gather kernel writes each output voxel ONCE with plain stores (no f32
// atomics -- R0 showed 51.2M scalar atomicAdds were 90% of runtime).
//
// ws layout (bytes):
//   [0,   512)              stats: sum[64], sumsq[64]          (zeroed)
//   [512, 1024)             scale a[64], shift b[64]           (finalize out)
//   [1024, +4*num_out)      cnt   (zeroed)
//   next  4*num_out         off   (exclusive scan; mutated to "end" by scatter)
//   next  4096              partials (block sums for 2-level scan)
//   next  4*n_vox           perm
// ===========================================================================

__global__ void hist_kernel(const int* __restrict__ out_idx,
                            int* __restrict__ cnt, int n)
{
    int i = blockIdx.x * 256 + threadIdx.x;
    if (i < n) atomicAdd(&cnt[out_idx[i]], 1);
}

// Block b sums cnt[b*4096 .. b*4096+4096) -> partials[b]
__global__ __launch_bounds__(256) void scan_partial(
    const int* __restrict__ cnt, int* __restrict__ partials, int num_out)
{
    __shared__ int s[256];
    const int base = blockIdx.x * 4096;
    int sum = 0;
    for (int k = threadIdx.x; k < 4096; k += 256) {
        int idx = base + k;
        if (idx < num_out) sum += cnt[idx];
    }
    s[threadIdx.x] = sum;
    __syncthreads();
    for (int d = 128; d > 0; d >>= 1) {
        if (threadIdx.x < d) s[threadIdx.x] += s[threadIdx.x + d];
        __syncthreads();
    }
    if (threadIdx.x == 0) partials[blockIdx.x] = s[0];
}

// Single block: in-place exclusive scan of partials[0..nb), nb <= 1024.
__global__ __launch_bounds__(256) void scan_root(int* __restrict__ partials, int nb)
{
    __shared__ int s[256];
    const int t = threadIdx.x;
    int vals[4]; int tsum = 0;
#pragma unroll
    for (int k = 0; k < 4; ++k) {
        int i = t * 4 + k;
        vals[k] = (i < nb) ? partials[i] : 0;
        tsum += vals[k];
    }
    s[t] = tsum;
    __syncthreads();
    for (int d = 1; d < 256; d <<= 1) {
        int v = (t >= d) ? s[t - d] : 0;
        __syncthreads();
        s[t] += v;
        __syncthreads();
    }
    int run = s[t] - tsum;   // exclusive prefix of this thread's chunk
#pragma unroll
    for (int k = 0; k < 4; ++k) {
        int i = t * 4 + k;
        if (i < nb) partials[i] = run;
        run += vals[k];
    }
}

// Block b writes exclusive offsets for cnt[b*4096 ..) using scanned partials.
__global__ __launch_bounds__(256) void scan_final(
    const int* __restrict__ cnt, const int* __restrict__ partials,
    int* __restrict__ off, int num_out)
{
    __shared__ int s[256];
    const int t = threadIdx.x;
    const int base = blockIdx.x * 4096 + t * 16;
    int vals[16]; int tsum = 0;
#pragma unroll
    for (int k = 0; k < 16; ++k) {
        int idx = base + k;
        int v = (idx < num_out) ? cnt[idx] : 0;
        vals[k] = v; tsum += v;
    }
    s[t] = tsum;
    __syncthreads();
    for (int d = 1; d < 256; d <<= 1) {
        int v = (t >= d) ? s[t - d] : 0;
        __syncthreads();
        s[t] += v;
        __syncthreads();
    }
    int run = partials[blockIdx.x] + (s[t] - tsum);
#pragma unroll
    for (int k = 0; k < 16; ++k) {
        int idx = base + k;
        if (idx < num_out) off[idx] = run;
        run += vals[k];
    }
}

// perm[pos] = input index; off[o] mutates from start -> end position.
__global__ void scatter_kernel(const int* __restrict__ out_idx,
                               int* __restrict__ off, int* __restrict__ perm, int n)
{
    int i = blockIdx.x * 256 + threadIdx.x;
    if (i < n) {
        int pos = atomicAdd(&off[out_idx[i]], 1);
        perm[pos] = i;
    }
}

// ---------------------------------------------------------------------------
// Gather-conv: one thread per OUTPUT voxel. W (64KB) in LDS with the
// (g+j)&15 swizzle (0 conflicts measured in R0). Plain stores, no atomics.
// After scatter_kernel, off[o] == end; start = end - cnt[o].
// ---------------------------------------------------------------------------
__global__ __launch_bounds__(256) void gather_conv(
    const float* __restrict__ x, const float* __restrict__ W,
    const int* __restrict__ k_idx, const int* __restrict__ perm,
    const int* __restrict__ off, const int* __restrict__ cnt,
    float* __restrict__ out, int num_out)
{
    __shared__ float4 sW[4096];               // 8 * 32 * 16 float4 = 64 KB
    const float4* Wv = (const float4*)W;      // Wv[j*512 + k*16 + g]
    for (int i = threadIdx.x; i < 4096; i += 256) {
        int g = i & 15;
        int j = i >> 9;
        sW[(i & ~15) | ((g + j) & 15)] = Wv[i];
    }
    __syncthreads();

    const int o = blockIdx.x * 256 + threadIdx.x;
    if (o >= num_out) return;

    const int end   = off[o];
    const int start = end - cnt[o];

    float4 acc[16];
#pragma unroll
    for (int g = 0; g < 16; ++g) acc[g] = make_float4(0.f, 0.f, 0.f, 0.f);

    for (int e = start; e < end; ++e) {
        const int v = perm[e];
        const int j = k_idx[v];
        const float4* xp = (const float4*)(x + (size_t)v * 32);
        const int base = j << 9;
#pragma unroll
        for (int ko = 0; ko < 8; ++ko) {
            const float4 xk4 = xp[ko];
#pragma unroll
            for (int ki = 0; ki < 4; ++ki) {
                const float xk = (ki == 0) ? xk4.x : (ki == 1) ? xk4.y
                               : (ki == 2) ? xk4.z : xk4.w;
                const int rowbase = base + ((ko * 4 + ki) << 4);
#pragma unroll
                for (int g = 0; g < 16; ++g) {
                    const float4 w = sW[rowbase + ((g + j) & 15)];
                    acc[g].x = fmaf(xk, w.x, acc[g].x);
                    acc[g].y = fmaf(xk, w.y, acc[g].y);
                    acc[g].z = fmaf(xk, w.z, acc[g].z);
                    acc[g].w = fmaf(xk, w.w, acc[g].w);
                }
            }
        }
    }

    float4* ob = (float4*)(out + (size_t)o * 64);
#pragma unroll
    for (int g = 0; g < 16; ++g) ob[g] = acc[g];
}

// ---------------------------------------------------------------------------
// Per-channel sum / sumsq over outputs. ws[0..63]=sum, ws[64..127]=sumsq.
// ---------------------------------------------------------------------------
__global__ __launch_bounds__(256) void stats_kernel(
    const float* __restrict__ out, float* __restrict__ ws, int num_out)
{
    __shared__ float s_red[128];
    if (threadIdx.x < 128) s_red[threadIdx.x] = 0.f;
    __syncthreads();

    const int cg   = threadIdx.x & 15;
    const int rowt = threadIdx.x >> 4;

    float4 sum = make_float4(0.f, 0.f, 0.f, 0.f);
    float4 sq  = make_float4(0.f, 0.f, 0.f, 0.f);
    const float4* o4 = (const float4*)out;
    for (int r = blockIdx.x * 16 + rowt; r < num_out; r += gridDim.x * 16) {
        const float4 v = o4[(size_t)r * 16 + cg];
        sum.x += v.x; sum.y += v.y; sum.z += v.z; sum.w += v.w;
        sq.x  += v.x * v.x; sq.y += v.y * v.y;
        sq.z  += v.z * v.z; sq.w += v.w * v.w;
    }

    atomicAdd(&s_red[4 * cg + 0], sum.x);
    atomicAdd(&s_red[4 * cg + 1], sum.y);
    atomicAdd(&s_red[4 * cg + 2], sum.z);
    atomicAdd(&s_red[4 * cg + 3], sum.w);
    atomicAdd(&s_red[64 + 4 * cg + 0], sq.x);
    atomicAdd(&s_red[64 + 4 * cg + 1], sq.y);
    atomicAdd(&s_red[64 + 4 * cg + 2], sq.z);
    atomicAdd(&s_red[64 + 4 * cg + 3], sq.w);
    __syncthreads();

    if (threadIdx.x < 128) atomicAdd(&ws[threadIdx.x], s_red[threadIdx.x]);
}

// a = gamma*rsqrt(var+eps); b = beta - mean_acc*a   (conv bias cancels in BN)
__global__ void finalize_kernel(const float* __restrict__ gamma,
                                const float* __restrict__ beta,
                                float* __restrict__ ws, float inv_n)
{
    const int c = threadIdx.x;   // 64 threads
    const float mean_acc = ws[c] * inv_n;
    const float var = ws[64 + c] * inv_n - mean_acc * mean_acc;
    const float a = gamma[c] * rsqrtf(var + EPS_BN);
    ws[128 + c] = a;
    ws[192 + c] = beta[c] - mean_acc * a;
}

__global__ __launch_bounds__(256) void apply_kernel(
    float* __restrict__ out, const float* __restrict__ ws, int n4)
{
    const int tid = blockIdx.x * 256 + threadIdx.x;
    const int stride = gridDim.x * 256;          // multiple of 16 -> cg fixed
    const int cg = tid & 15;
    const float4 a = ((const float4*)(ws + 128))[cg];
    const float4 b = ((const float4*)(ws + 192))[cg];
    float4* o4 = (float4*)out;
    for (int i = tid; i < n4; i += stride) {
        float4 v = o4[i];
        v.x = fmaxf(fmaf(v.x, a.x, b.x), 0.f);
        v.y = fmaxf(fmaf(v.y, a.y, b.y), 0.f);
        v.z = fmaxf(fmaf(v.z, a.z, b.z), 0.f);
        v.w = fmaxf(fmaf(v.w, a.w, b.w), 0.f);
        o4[i] = v;
    }
}

extern "C" void kernel_launch(void* const* d_in, const int* in_sizes, int n_in,
                              void* d_out, int out_size, void* d_ws, size_t ws_size,
                              hipStream_t stream)
{
    const float* x     = (const float*)d_in[0];
    const float* W     = (const float*)d_in[1];
    // d_in[2] = bias: cancels under BN, unused.
    const float* gamma = (const float*)d_in[3];
    const float* beta  = (const float*)d_in[4];
    const int* k_idx   = (const int*)d_in[5];
    const int* out_idx = (const int*)d_in[6];

    const int n_vox   = in_sizes[5];
    const int num_out = out_size / 64;
    float* out  = (float*)d_out;
    float* ws_f = (float*)d_ws;

    char* p = (char*)d_ws;
    int* cnt      = (int*)(p + 1024);
    int* off      = cnt + num_out;
    int* partials = off + num_out;
    int* perm     = partials + 1024;

    const int nb_chunks = (num_out + 4095) / 4096;   // blocks for scan (<=1024)
    const int nb_vox    = (n_vox + 255) / 256;
    const int nb_out    = (num_out + 255) / 256;

    hipMemsetAsync(d_ws, 0, 512, stream);                          // stats
    hipMemsetAsync(cnt, 0, (size_t)num_out * sizeof(int), stream); // histogram

    hist_kernel <<<nb_vox, 256, 0, stream>>>(out_idx, cnt, n_vox);
    scan_partial<<<nb_chunks, 256, 0, stream>>>(cnt, partials, num_out);
    scan_root   <<<1, 256, 0, stream>>>(partials, nb_chunks);
    scan_final  <<<nb_chunks, 256, 0, stream>>>(cnt, partials, off, num_out);
    scatter_kernel<<<nb_vox, 256, 0, stream>>>(out_idx, off, perm, n_vox);
    gather_conv <<<nb_out, 256, 0, stream>>>(x, W, k_idx, perm, off, cnt, out, num_out);
    stats_kernel<<<256, 256, 0, stream>>>(out, ws_f, num_out);
    finalize_kernel<<<1, 64, 0, stream>>>(gamma, beta, ws_f, 1.0f / (float)num_out);
    apply_kernel<<<1024, 256, 0, stream>>>(out, ws_f, out_size / 4);
}

// Round 3
// 591.592 us; speedup vs baseline: 5.2228x; 1.1395x over previous
//
#include <hip/hip_runtime.h>

#define EPS_BN 1e-5f

// ===========================================================================
// R2: linked-list map inversion (1 kernel, replaces hist+scan*3+scatter CSR)
// + higher-occupancy gather (512 thr, VGPR<=128 -> 16 waves/CU vs 8).
//
// head[o] / next[v] store packed links: L = v | (k_idx[v] << 24), -1 = end.
// gather_conv never touches k_idx/perm/cnt: chain is head -> (v,j) -> x.
//
// ws layout (bytes):
//   [0,   512)        stats: sum[64], sumsq[64]   (zeroed)
//   [512, 1024)       scale a[64], shift b[64]    (finalize out)
//   [1024, +4*num_out) head   (memset 0xFF = -1)
//   next 4*n_vox      next   (no init: written for every i before any read)
// ===========================================================================

__global__ void scatter_ll(const int* __restrict__ out_idx,
                           const int* __restrict__ k_idx,
                           int* __restrict__ head, int* __restrict__ next, int n)
{
    int i = blockIdx.x * 256 + threadIdx.x;
    if (i < n) {
        int L = i | (k_idx[i] << 24);
        int old = atomicExch(&head[out_idx[i]], L);
        next[i] = old;
    }
}

// ---------------------------------------------------------------------------
// Gather-conv: one thread per OUTPUT voxel. W (64KB fp32) in LDS with the
// (g+j)&15 swizzle (0 conflicts measured R0/R1). Plain stores, no atomics.
// ---------------------------------------------------------------------------
__global__ __launch_bounds__(512, 4) void gather_conv(
    const float* __restrict__ x, const float* __restrict__ W,
    const int* __restrict__ head, const int* __restrict__ next,
    float* __restrict__ out, int num_out)
{
    __shared__ float4 sW[4096];               // 8 * 32 * 16 float4 = 64 KB
    const int o = blockIdx.x * 512 + threadIdx.x;

    // Issue the head load before W staging so it overlaps the LDS fill.
    int L = (o < num_out) ? head[o] : -1;

    const float4* Wv = (const float4*)W;      // Wv[j*512 + k*16 + g]
    for (int i = threadIdx.x; i < 4096; i += 512) {
        int g = i & 15;
        int j = i >> 9;
        sW[(i & ~15) | ((g + j) & 15)] = Wv[i];
    }
    __syncthreads();

    if (o >= num_out) return;

    float4 acc[16];
#pragma unroll
    for (int g = 0; g < 16; ++g) acc[g] = make_float4(0.f, 0.f, 0.f, 0.f);

    while (L >= 0) {
        const int v = L & 0xFFFFFF;
        const int j = L >> 24;
        const int Ln = next[v];               // prefetch under the FMAs
        const float4* xp = (const float4*)(x + (size_t)v * 32);
        const int base = j << 9;
#pragma unroll
        for (int ko = 0; ko < 8; ++ko) {
            const float4 xk4 = xp[ko];
#pragma unroll
            for (int ki = 0; ki < 4; ++ki) {
                const float xk = (ki == 0) ? xk4.x : (ki == 1) ? xk4.y
                               : (ki == 2) ? xk4.z : xk4.w;
                const int rowbase = base + ((ko * 4 + ki) << 4);
#pragma unroll
                for (int g = 0; g < 16; ++g) {
                    const float4 w = sW[rowbase + ((g + j) & 15)];
                    acc[g].x = fmaf(xk, w.x, acc[g].x);
                    acc[g].y = fmaf(xk, w.y, acc[g].y);
                    acc[g].z = fmaf(xk, w.z, acc[g].z);
                    acc[g].w = fmaf(xk, w.w, acc[g].w);
                }
            }
        }
        L = Ln;
    }

    float4* ob = (float4*)(out + (size_t)o * 64);
#pragma unroll
    for (int g = 0; g < 16; ++g) ob[g] = acc[g];
}

// ---------------------------------------------------------------------------
// Per-channel sum / sumsq over outputs. ws[0..63]=sum, ws[64..127]=sumsq.
// ---------------------------------------------------------------------------
__global__ __launch_bounds__(256) void stats_kernel(
    const float* __restrict__ out, float* __restrict__ ws, int num_out)
{
    __shared__ float s_red[128];
    if (threadIdx.x < 128) s_red[threadIdx.x] = 0.f;
    __syncthreads();

    const int cg   = threadIdx.x & 15;
    const int rowt = threadIdx.x >> 4;

    float4 sum = make_float4(0.f, 0.f, 0.f, 0.f);
    float4 sq  = make_float4(0.f, 0.f, 0.f, 0.f);
    const float4* o4 = (const float4*)out;
    for (int r = blockIdx.x * 16 + rowt; r < num_out; r += gridDim.x * 16) {
        const float4 v = o4[(size_t)r * 16 + cg];
        sum.x += v.x; sum.y += v.y; sum.z += v.z; sum.w += v.w;
        sq.x  += v.x * v.x; sq.y += v.y * v.y;
        sq.z  += v.z * v.z; sq.w += v.w * v.w;
    }

    atomicAdd(&s_red[4 * cg + 0], sum.x);
    atomicAdd(&s_red[4 * cg + 1], sum.y);
    atomicAdd(&s_red[4 * cg + 2], sum.z);
    atomicAdd(&s_red[4 * cg + 3], sum.w);
    atomicAdd(&s_red[64 + 4 * cg + 0], sq.x);
    atomicAdd(&s_red[64 + 4 * cg + 1], sq.y);
    atomicAdd(&s_red[64 + 4 * cg + 2], sq.z);
    atomicAdd(&s_red[64 + 4 * cg + 3], sq.w);
    __syncthreads();

    if (threadIdx.x < 128) atomicAdd(&ws[threadIdx.x], s_red[threadIdx.x]);
}

// a = gamma*rsqrt(var+eps); b = beta - mean_acc*a   (conv bias cancels in BN)
__global__ void finalize_kernel(const float* __restrict__ gamma,
                                const float* __restrict__ beta,
                                float* __restrict__ ws, float inv_n)
{
    const int c = threadIdx.x;   // 64 threads
    const float mean_acc = ws[c] * inv_n;
    const float var = ws[64 + c] * inv_n - mean_acc * mean_acc;
    const float a = gamma[c] * rsqrtf(var + EPS_BN);
    ws[128 + c] = a;
    ws[192 + c] = beta[c] - mean_acc * a;
}

__global__ __launch_bounds__(256) void apply_kernel(
    float* __restrict__ out, const float* __restrict__ ws, int n4)
{
    const int tid = blockIdx.x * 256 + threadIdx.x;
    const int stride = gridDim.x * 256;          // multiple of 16 -> cg fixed
    const int cg = tid & 15;
    const float4 a = ((const float4*)(ws + 128))[cg];
    const float4 b = ((const float4*)(ws + 192))[cg];
    float4* o4 = (float4*)out;
    for (int i = tid; i < n4; i += stride) {
        float4 v = o4[i];
        v.x = fmaxf(fmaf(v.x, a.x, b.x), 0.f);
        v.y = fmaxf(fmaf(v.y, a.y, b.y), 0.f);
        v.z = fmaxf(fmaf(v.z, a.z, b.z), 0.f);
        v.w = fmaxf(fmaf(v.w, a.w, b.w), 0.f);
        o4[i] = v;
    }
}

extern "C" void kernel_launch(void* const* d_in, const int* in_sizes, int n_in,
                              void* d_out, int out_size, void* d_ws, size_t ws_size,
                              hipStream_t stream)
{
    const float* x     = (const float*)d_in[0];
    const float* W     = (const float*)d_in[1];
    // d_in[2] = bias: cancels under BN, unused.
    const float* gamma = (const float*)d_in[3];
    const float* beta  = (const float*)d_in[4];
    const int* k_idx   = (const int*)d_in[5];
    const int* out_idx = (const int*)d_in[6];

    const int n_vox   = in_sizes[5];
    const int num_out = out_size / 64;
    float* out  = (float*)d_out;
    float* ws_f = (float*)d_ws;

    char* p = (char*)d_ws;
    int* head = (int*)(p + 1024);
    int* next = head + num_out;

    const int nb_vox = (n_vox + 255) / 256;
    const int nb_out = (num_out + 511) / 512;

    hipMemsetAsync(d_ws, 0, 512, stream);                             // stats
    hipMemsetAsync(head, 0xFF, (size_t)num_out * sizeof(int), stream); // -1

    scatter_ll <<<nb_vox, 256, 0, stream>>>(out_idx, k_idx, head, next, n_vox);
    gather_conv<<<nb_out, 512, 0, stream>>>(x, W, head, next, out, num_out);
    stats_kernel<<<256, 256, 0, stream>>>(out, ws_f, num_out);
    finalize_kernel<<<1, 64, 0, stream>>>(gamma, beta, ws_f, 1.0f / (float)num_out);
    apply_kernel<<<1024, 256, 0, stream>>>(out, ws_f, out_size / 4);
}

// Round 4
// 475.453 us; speedup vs baseline: 6.4985x; 1.2443x over previous
//
#include <hip/hip_runtime.h>

#define EPS_BN 1e-5f

typedef __attribute__((ext_vector_type(8))) short short8;   // 8 bf16 (4 VGPR)
typedef __attribute__((ext_vector_type(4))) float floatx4;  // MFMA C/D

__device__ __forceinline__ short f2bf(float f) {            // RNE f32->bf16
    unsigned u = __float_as_uint(f);
    u += 0x7FFF + ((u >> 16) & 1);
    return (short)(u >> 16);
}

// ===========================================================================
// R3: MFMA gather. slot[o*8+j] = input index (chained via next[] for dup
// coords). Wave = 16 outputs; j-loop uniform; A = 16 x-rows (bf16), B = W[j]
// packed in fragment order; 4x mfma_f32_16x16x32_bf16 per j. Stats fused.
//
// ws layout (bytes):
//   [512, 1024)   a[64], b[64] (finalize out)
//   [1024, +32K)  packedW: [j][tile][lane][8] bf16
//   then          partials: [128][nb] f32  (sum rows 0..63, sumsq 64..127)
//   then          slot: num_out*8 int (memset 0xFF)
//   then          next: n_vox int
// ===========================================================================

// Fragment-order W pack: packed[((j*4+t)*64+l)*8+i] = bf16(W[j][(l>>4)*8+i][(l&15)+16t])
__global__ void pack_W(const float* __restrict__ W, short* __restrict__ packed)
{
    for (int s = threadIdx.x; s < 2048; s += 256) {
        const int j = s >> 8, t = (s >> 6) & 3, l = s & 63;
        const int k0 = (l >> 4) * 8, c = (l & 15) + 16 * t;
        short8 v;
#pragma unroll
        for (int i = 0; i < 8; ++i)
            v[i] = f2bf(W[(j * 32 + k0 + i) * 64 + c]);
        ((short8*)packed)[s] = v;
    }
}

__global__ void scatter_slots(const int* __restrict__ out_idx,
                              const int* __restrict__ k_idx,
                              int* __restrict__ slot, int* __restrict__ next, int n)
{
    int i = blockIdx.x * 256 + threadIdx.x;
    if (i < n) {
        int old = atomicExch(&slot[(size_t)out_idx[i] * 8 + k_idx[i]], i);
        next[i] = old;
    }
}

// ---------------------------------------------------------------------------
// MFMA gather: block = 4 waves x 16 outputs. Writes pre-BN y to out and
// per-block channel partial sums/sumsq to partials.
// ---------------------------------------------------------------------------
__global__ __launch_bounds__(256, 4) void gather_mfma(
    const float* __restrict__ x, const short* __restrict__ packedW,
    const int* __restrict__ slot, const int* __restrict__ next_arr,
    float* __restrict__ out, float* __restrict__ partials,
    int num_out, int nb)
{
    __shared__ short sW[16384];          // 32 KB: [j][tile][lane][8]
    __shared__ float s_stat[128];

    const int tid = threadIdx.x;
    if (tid < 128) s_stat[tid] = 0.f;
    for (int i = tid; i < 2048; i += 256)
        ((short8*)sW)[i] = ((const short8*)packedW)[i];
    __syncthreads();

    const int wave = tid >> 6, lane = tid & 63;
    const int quad = lane >> 4, row = lane & 15;
    const int obase = blockIdx.x * 64 + wave * 16;
    const int o = obase + row;
    const bool valid_o = (o < num_out);

    // 8 slots for this output row (32B, cache-served; 4 quads redundant-load)
    int4 sl0 = make_int4(-1, -1, -1, -1), sl1 = sl0;
    if (valid_o) {
        const int4* sp = (const int4*)(slot + (size_t)o * 8);
        sl0 = sp[0]; sl1 = sp[1];
    }

    floatx4 acc[4] = {{0,0,0,0},{0,0,0,0},{0,0,0,0},{0,0,0,0}};
    const short8* bw = (const short8*)sW;

#pragma unroll
    for (int j = 0; j < 8; ++j) {
        const int v = (j < 4) ? ((j == 0) ? sl0.x : (j == 1) ? sl0.y : (j == 2) ? sl0.z : sl0.w)
                              : ((j == 4) ? sl1.x : (j == 5) ? sl1.y : (j == 6) ? sl1.z : sl1.w);
        float4 xa = make_float4(0.f, 0.f, 0.f, 0.f), xb = xa;
        int w = -1;
        if (v >= 0) {
            const float4* xp = (const float4*)(x + (size_t)v * 32) + quad * 2;
            xa = xp[0]; xb = xp[1];
            w = next_arr[v];
        }
        while (__any(w >= 0)) {          // duplicate-coord chain (rare)
            if (w >= 0) {
                const float4* xp2 = (const float4*)(x + (size_t)w * 32) + quad * 2;
                float4 ya = xp2[0], yb = xp2[1];
                xa.x += ya.x; xa.y += ya.y; xa.z += ya.z; xa.w += ya.w;
                xb.x += yb.x; xb.y += yb.y; xb.z += yb.z; xb.w += yb.w;
                w = next_arr[w];
            }
        }
        short8 afrag;
        afrag[0] = f2bf(xa.x); afrag[1] = f2bf(xa.y);
        afrag[2] = f2bf(xa.z); afrag[3] = f2bf(xa.w);
        afrag[4] = f2bf(xb.x); afrag[5] = f2bf(xb.y);
        afrag[6] = f2bf(xb.z); afrag[7] = f2bf(xb.w);

        const int jb = j * 256;
#pragma unroll
        for (int t = 0; t < 4; ++t) {
            const short8 bfrag = bw[jb + t * 64 + lane];
            acc[t] = __builtin_amdgcn_mfma_f32_16x16x32_bf16(afrag, bfrag, acc[t], 0, 0, 0);
        }
    }

    // Epilogue: C layout col=lane&15, row=quad*4+reg. Store + fused stats.
#pragma unroll
    for (int t = 0; t < 4; ++t) {
        const int c = (lane & 15) + 16 * t;
        float sum = 0.f, sq = 0.f;
#pragma unroll
        for (int r = 0; r < 4; ++r) {
            const int oc = obase + quad * 4 + r;
            const float val = acc[t][r];
            if (oc < num_out) {
                out[(size_t)oc * 64 + c] = val;
                sum += val; sq += val * val;
            }
        }
        sum += __shfl_xor(sum, 16, 64); sum += __shfl_xor(sum, 32, 64);
        sq  += __shfl_xor(sq, 16, 64);  sq  += __shfl_xor(sq, 32, 64);
        if (quad == 0) {
            atomicAdd(&s_stat[c], sum);
            atomicAdd(&s_stat[64 + c], sq);
        }
    }
    __syncthreads();
    if (tid < 128) partials[(size_t)tid * nb + blockIdx.x] = s_stat[tid];
}

// One block per channel c: reduce partials, emit a[c], b[c].
// (conv bias cancels under BN: final = (acc-mean)*rsqrt(var)*gamma+beta)
__global__ __launch_bounds__(256) void reduce_finalize(
    const float* __restrict__ partials, const float* __restrict__ gamma,
    const float* __restrict__ beta, float* __restrict__ ws_ab,
    int nb, float inv_n)
{
    __shared__ float r1[256], r2[256];
    const int c = blockIdx.x, t = threadIdx.x;
    float s1 = 0.f, s2 = 0.f;
    for (int i = t; i < nb; i += 256) {
        s1 += partials[(size_t)c * nb + i];
        s2 += partials[(size_t)(c + 64) * nb + i];
    }
    r1[t] = s1; r2[t] = s2;
    __syncthreads();
    for (int d = 128; d > 0; d >>= 1) {
        if (t < d) { r1[t] += r1[t + d]; r2[t] += r2[t + d]; }
        __syncthreads();
    }
    if (t == 0) {
        const float mean = r1[0] * inv_n;
        const float var = r2[0] * inv_n - mean * mean;
        const float a = gamma[c] * rsqrtf(var + EPS_BN);
        ws_ab[c] = a;               // a[64]
        ws_ab[64 + c] = beta[c] - mean * a;  // b[64]
    }
}

__global__ __launch_bounds__(256) void apply_kernel(
    float* __restrict__ out, const float* __restrict__ ws_ab, int n4)
{
    const int tid = blockIdx.x * 256 + threadIdx.x;
    const int stride = gridDim.x * 256;          // multiple of 16 -> cg fixed
    const int cg = tid & 15;
    const float4 a = ((const float4*)ws_ab)[cg];
    const float4 b = ((const float4*)(ws_ab + 64))[cg];
    float4* o4 = (float4*)out;
    for (int i = tid; i < n4; i += stride) {
        float4 v = o4[i];
        v.x = fmaxf(fmaf(v.x, a.x, b.x), 0.f);
        v.y = fmaxf(fmaf(v.y, a.y, b.y), 0.f);
        v.z = fmaxf(fmaf(v.z, a.z, b.z), 0.f);
        v.w = fmaxf(fmaf(v.w, a.w, b.w), 0.f);
        o4[i] = v;
    }
}

extern "C" void kernel_launch(void* const* d_in, const int* in_sizes, int n_in,
                              void* d_out, int out_size, void* d_ws, size_t ws_size,
                              hipStream_t stream)
{
    const float* x     = (const float*)d_in[0];
    const float* W     = (const float*)d_in[1];
    // d_in[2] = bias: cancels under BN, unused.
    const float* gamma = (const float*)d_in[3];
    const float* beta  = (const float*)d_in[4];
    const int* k_idx   = (const int*)d_in[5];
    const int* out_idx = (const int*)d_in[6];

    const int n_vox   = in_sizes[5];
    const int num_out = out_size / 64;
    const int nb      = (num_out + 63) / 64;     // gather blocks
    float* out = (float*)d_out;

    char* p = (char*)d_ws;
    float* ws_ab    = (float*)(p + 512);                 // a[64], b[64]
    short* packedW  = (short*)(p + 1024);                // 32 KB
    float* partials = (float*)(p + 1024 + 32768);        // 128*nb f32
    char*  p2       = p + 1024 + 32768 + (size_t)128 * nb * 4;
    int*   slot     = (int*)p2;                          // num_out*8
    int*   next     = slot + (size_t)num_out * 8;        // n_vox

    hipMemsetAsync(slot, 0xFF, (size_t)num_out * 8 * sizeof(int), stream);

    pack_W        <<<1, 256, 0, stream>>>(W, packedW);
    scatter_slots <<<(n_vox + 255) / 256, 256, 0, stream>>>(out_idx, k_idx, slot, next, n_vox);
    gather_mfma   <<<nb, 256, 0, stream>>>(x, packedW, slot, next, out, partials, num_out, nb);
    reduce_finalize<<<64, 256, 0, stream>>>(partials, gamma, beta, ws_ab, nb, 1.0f / (float)num_out);
    apply_kernel  <<<1024, 256, 0, stream>>>(out, ws_ab, out_size / 4);
}